// Round 2
// baseline (583.785 us; speedup 1.0000x reference)
//
#include <hip/hip_runtime.h>
#include <math.h>

// LIF_R_ASC recurrent spiking-neuron scan — fp64 state recursion.
// T=1024 serial steps; B=2048 batch x N=12 neurons parallel.
// 16 lanes per batch element (lane = neuron, 4 pad lanes); wave64 = 4 batch
// elements. State in fp64 registers to track the numpy float64 reference
// bit-closely (spike threshold crossings are the chaotic amplifier — fp32
// rounding-order differences flip spikes; fp64 makes flip prob ~1e-9).
// Output sigmoid is output-only -> fp32 expf.

#define T_STEPS 1024
#define BATCH   2048
#define NN      12
#define PF      8

__global__ __launch_bounds__(64) void lif_scan_kernel(
    const float* __restrict__ x,        // [T,B,N]
    const float* __restrict__ w,        // [N,N]
    const float* __restrict__ E_L,      // [N]
    const float* __restrict__ tau_m,    // [N]
    const float* __restrict__ tau_s,    // [N]
    const float* __restrict__ Gp,       // [N]
    const float* __restrict__ f_v,      // [N]
    const float* __restrict__ f_I,      // [N]
    const float* __restrict__ dth_s,    // [N]
    const float* __restrict__ b_s,      // [N]
    const float* __restrict__ delta_V,  // [N]
    const float* __restrict__ nRc,      // [N]
    const int*   __restrict__ ntypes,   // [N]
    float* __restrict__ out)            // [T,B,N]
{
    const int lane = threadIdx.x;        // 0..63, block = 1 wave
    const int g    = lane >> 4;          // group within wave: 0..3
    const int n    = lane & 15;          // neuron slot: 0..15
    const int nn   = (n < NN) ? n : 0;   // clamp for pad lanes
    const bool act = (n < NN);
    const int b    = blockIdx.x * 4 + g; // batch element

    // ---- per-lane (per-neuron) constants in fp64 ----
    const double EL   = (double)E_L[nn];
    const double GG   = (double)Gp[nn];
    const double fv   = (double)f_v[nn];
    const double fI   = (double)f_I[nn];
    const double DTH  = (double)dth_s[nn];
    const double bs   = (double)b_s[nn];
    const double dV   = (double)delta_V[nn];
    const double nR   = (double)nRc[nn];
    const double inv_taum = 1.0 / (double)tau_m[nn];
    const double inv_taus = 1.0 / (double)tau_s[nn];
    const double one_m_bs = 1.0 - bs;

    // ---- weight column: Wm[i][n] = w[i][n]*nt[i], zero diagonal ----
    double Wcol[NN];
#pragma unroll
    for (int i = 0; i < NN; ++i) {
        double wv = (double)w[i * NN + nn] * (double)ntypes[i];
        if (i == nn) wv = 0.0;
        Wcol[i] = wv;
    }

    // ---- state (fp64) ----
    double v  = EL;
    double s  = 0.0;
    double th = DTH;
    double Ia = 0.0;

    const int strideT = BATCH * NN;                 // 24576 floats per timestep
    const float* xp = x + b * NN + nn;              // this thread's x column
    float* op = out + b * NN + n;                   // this thread's out column

    // ---- x prefetch buffer (fp32 loads) ----
    float xbuf[PF];
#pragma unroll
    for (int k = 0; k < PF; ++k)
        xbuf[k] = xp[k * strideT];

    for (int t0 = 0; t0 < T_STEPS; t0 += PF) {
#pragma unroll
        for (int k = 0; k < PF; ++k) {
            const int t = t0 + k;
            const float xcur = xbuf[k];
            int tn = t + PF;
            if (tn >= T_STEPS) tn = T_STEPS - 1;
            xbuf[k] = xp[tn * strideT];

            // ---- one LIF step (fp64), mirroring reference op order ----
            const double a = (Ia + s) * 0.5;

            double I = 0.0;
#pragma unroll
            for (int i = 0; i < NN; ++i) {
                const double ai = __shfl(a, i, 16); // broadcast lane i of group
                I += ai * Wcol[i];
            }
            I += 1.75 * (double)xcur;

            const double dv     = (GG * (EL - v) + I * nR) * inv_taum;
            const double v_next = v + dv;
            const bool   spiked = (v_next >= th);

            double gating = v_next / th;
            gating = fmin(fmax(gating, 0.0), 1.0);

            const double dv_max = th - EL;
            double rr = dv / dv_max;
            rr = fmin(fmax(rr, 0.0), 1.0);

            s = s + (-s + gating * rr) * inv_taus;

            const double v_reset = EL + fv * (v - EL) - dV;
            const double th_new  = spiked ? (th + DTH) : (one_m_bs * th);

            v  = spiked ? v_reset : v_next;
            Ia = Ia - fI * Ia + (spiked ? fI : 0.0);

            // output (does not feed back into state) — fp32 sigmoid
            const float z    = (float)(v_next - th_new);
            th = th_new;
            const float soft = 1.0f / (1.0f + expf(-z));

            if (act)
                op[t * strideT] = soft;
        }
    }
}

extern "C" void kernel_launch(void* const* d_in, const int* in_sizes, int n_in,
                              void* d_out, int out_size, void* d_ws, size_t ws_size,
                              hipStream_t stream) {
    const float* x    = (const float*)d_in[0];
    const float* w    = (const float*)d_in[1];
    const float* E_L  = (const float*)d_in[2];
    const float* taum = (const float*)d_in[3];
    const float* taus = (const float*)d_in[4];
    const float* G    = (const float*)d_in[5];
    const float* f_v  = (const float*)d_in[6];
    const float* f_I  = (const float*)d_in[7];
    const float* dth  = (const float*)d_in[8];
    const float* b_s  = (const float*)d_in[9];
    const float* dV   = (const float*)d_in[10];
    const float* nRc  = (const float*)d_in[11];
    const int*   nt   = (const int*)d_in[12];
    float* outp       = (float*)d_out;

    const int blocks = BATCH / 4;  // 512 blocks x 64 threads
    lif_scan_kernel<<<blocks, 64, 0, stream>>>(
        x, w, E_L, taum, taus, G, f_v, f_I, dth, b_s, dV, nRc, nt, outp);
}

// Round 3
// 493.376 us; speedup vs baseline: 1.1832x; 1.1832x over previous
//
#include <hip/hip_runtime.h>
#include <math.h>
#include <type_traits>

// LIF_R_ASC recurrent spiking-neuron scan — fp64 state, latency-optimized.
// 16 lanes/batch (lane=neuron), wave64 = 4 batch elems, 512 blocks x 64.
// Wall time = per-wave serial chain (all waves co-resident). Chain shortened:
//  - DPP row_newbcast (0x150+i) for 16-lane broadcast (VALU path, ~8cyc)
//    with runtime self-check fallback to __shfl (DS path) if DPP misbehaves.
//  - dot = 12 independent products + 4-level tree (was 12 chained FMAs)
//  - gating/rr divides -> multiply by reciprocals computed at END of previous
//    step (depend only on th; overlap next step's broadcast+dot). <=1.5ulp
//    fp64 difference — no spike-flip risk.

#define T_STEPS 1024
#define BATCH   2048
#define NN      12
#define PF      8

template<int I>
__device__ __forceinline__ double rowbcast16(double x) {
    union { double d; int i2[2]; } u, r;
    u.d = x;
    r.i2[0] = __builtin_amdgcn_update_dpp(0, u.i2[0], 0x150 + I, 0xF, 0xF, true);
    r.i2[1] = __builtin_amdgcn_update_dpp(0, u.i2[1], 0x150 + I, 0xF, 0xF, true);
    return r.d;
}

template<bool USE_DPP, int I>
__device__ __forceinline__ double bc(double a) {
    if constexpr (USE_DPP) return rowbcast16<I>(a);
    else                   return __shfl(a, I, 16);
}

__global__ __launch_bounds__(64) void lif_scan_kernel(
    const float* __restrict__ x,        // [T,B,N]
    const float* __restrict__ w,        // [N,N]
    const float* __restrict__ E_L,
    const float* __restrict__ tau_m,
    const float* __restrict__ tau_s,
    const float* __restrict__ Gp,
    const float* __restrict__ f_v,
    const float* __restrict__ f_I,
    const float* __restrict__ dth_s,
    const float* __restrict__ b_s,
    const float* __restrict__ delta_V,
    const float* __restrict__ nRc,
    const int*   __restrict__ ntypes,
    float* __restrict__ out)            // [T,B,N]
{
    const int lane = threadIdx.x;        // block = 1 wave
    const int g    = lane >> 4;          // group (batch within wave): 0..3
    const int n    = lane & 15;          // neuron slot
    const int nn   = (n < NN) ? n : 0;
    const bool act = (n < NN);
    const int b    = blockIdx.x * 4 + g;

    // per-neuron constants (fp64)
    const double EL   = (double)E_L[nn];
    const double GG   = (double)Gp[nn];
    const double fv   = (double)f_v[nn];
    const double fI   = (double)f_I[nn];
    const double DTH  = (double)dth_s[nn];
    const double bs   = (double)b_s[nn];
    const double dV   = (double)delta_V[nn];
    const double nR   = (double)nRc[nn];
    const double inv_taum = 1.0 / (double)tau_m[nn];
    const double inv_taus = 1.0 / (double)tau_s[nn];
    const double one_m_bs = 1.0 - bs;

    // weight column: Wm[i][n] = w[i][n]*nt[i], zero diag
    double W[NN];
#pragma unroll
    for (int i = 0; i < NN; ++i) {
        double wv = (double)w[i * NN + nn] * (double)ntypes[i];
        if (i == nn) wv = 0.0;
        W[i] = wv;
    }

    // state
    double v  = EL;
    double s  = 0.0;
    double th = DTH;
    double Ia = 0.0;
    double inv_th    = 1.0 / th;
    double inv_dvmax = 1.0 / (th - EL);

    const int strideT = BATCH * NN;
    const float* xp = x + b * NN + nn;
    float* op = out + b * NN + n;

    float xbuf[PF];
#pragma unroll
    for (int k = 0; k < PF; ++k)
        xbuf[k] = xp[k * strideT];

    // --- one-time DPP semantics self-check (uniform across all waves) ---
    bool dpp_ok;
    {
        double tv = (double)lane;
        double r5 = rowbcast16<5>(tv);
        bool ok = (r5 == (double)((lane & 48) + 5));
        dpp_ok = (__ballot(ok) == ~0ull);
    }

    auto body = [&](auto use_dpp_c) {
        constexpr bool USE_DPP = decltype(use_dpp_c)::value;
        for (int t0 = 0; t0 < T_STEPS; t0 += PF) {
#pragma unroll
            for (int k = 0; k < PF; ++k) {
                const int t = t0 + k;
                const float xcur = xbuf[k];
                int tn = t + PF;
                if (tn >= T_STEPS) tn = T_STEPS - 1;
                xbuf[k] = xp[tn * strideT];

                // a = (Ia + s)/2 ; broadcast + product tree
                const double a = (Ia + s) * 0.5;

                const double p0  = bc<USE_DPP, 0>(a) * W[0];
                const double p1  = bc<USE_DPP, 1>(a) * W[1];
                const double p2  = bc<USE_DPP, 2>(a) * W[2];
                const double p3  = bc<USE_DPP, 3>(a) * W[3];
                const double p4  = bc<USE_DPP, 4>(a) * W[4];
                const double p5  = bc<USE_DPP, 5>(a) * W[5];
                const double p6  = bc<USE_DPP, 6>(a) * W[6];
                const double p7  = bc<USE_DPP, 7>(a) * W[7];
                const double p8  = bc<USE_DPP, 8>(a) * W[8];
                const double p9  = bc<USE_DPP, 9>(a) * W[9];
                const double p10 = bc<USE_DPP,10>(a) * W[10];
                const double p11 = bc<USE_DPP,11>(a) * W[11];

                const double q01 = p0 + p1,  q23 = p2 + p3;
                const double q45 = p4 + p5,  q67 = p6 + p7;
                const double q89 = p8 + p9,  qAB = p10 + p11;
                const double h0 = q01 + q23, h1 = q45 + q67, h2 = q89 + qAB;
                const double I = ((h0 + h1) + h2) + 1.75 * (double)xcur;

                const double dv     = (GG * (EL - v) + I * nR) * inv_taum;
                const double v_next = v + dv;
                const bool   spiked = (v_next >= th);

                double gating = v_next * inv_th;            // ~= v_next/th
                gating = fmin(fmax(gating, 0.0), 1.0);
                double rr = dv * inv_dvmax;                 // ~= dv/(th-EL)
                rr = fmin(fmax(rr, 0.0), 1.0);

                s = s + (-s + gating * rr) * inv_taus;

                const double v_reset = EL + fv * (v - EL) - dV;
                const double th_new  = spiked ? (th + DTH) : (one_m_bs * th);

                v  = spiked ? v_reset : v_next;
                Ia = Ia - fI * Ia + (spiked ? fI : 0.0);

                th = th_new;
                // reciprocals for NEXT step — off critical path (overlap dot)
                inv_th    = 1.0 / th;
                inv_dvmax = 1.0 / (th - EL);

                const float z    = (float)(v_next - th_new);
                const float soft = 1.0f / (1.0f + expf(-z));
                if (act)
                    op[t * strideT] = soft;
            }
        }
    };

    if (dpp_ok) body(std::true_type{});
    else        body(std::false_type{});
}

extern "C" void kernel_launch(void* const* d_in, const int* in_sizes, int n_in,
                              void* d_out, int out_size, void* d_ws, size_t ws_size,
                              hipStream_t stream) {
    const float* x    = (const float*)d_in[0];
    const float* w    = (const float*)d_in[1];
    const float* E_L  = (const float*)d_in[2];
    const float* taum = (const float*)d_in[3];
    const float* taus = (const float*)d_in[4];
    const float* G    = (const float*)d_in[5];
    const float* f_v  = (const float*)d_in[6];
    const float* f_I  = (const float*)d_in[7];
    const float* dth  = (const float*)d_in[8];
    const float* b_s  = (const float*)d_in[9];
    const float* dV   = (const float*)d_in[10];
    const float* nRc  = (const float*)d_in[11];
    const int*   nt   = (const int*)d_in[12];
    float* outp       = (float*)d_out;

    const int blocks = BATCH / 4;  // 512 blocks x 64 threads
    lif_scan_kernel<<<blocks, 64, 0, stream>>>(
        x, w, E_L, taum, taus, G, f_v, f_I, dth, b_s, dV, nRc, nt, outp);
}

// Round 7
// 379.286 us; speedup vs baseline: 1.5392x; 1.3008x over previous
//
#include <hip/hip_runtime.h>
#include <math.h>
#include <type_traits>

// LIF_R_ASC recurrent spiking-neuron scan — fp64 state, issue-count-optimized.
// 16 lanes/batch (lane=neuron), wave64 = 4 batch elems, 512 blocks x 64.
// Latency/issue-bound: wall = per-wave serial chain. This rev cuts issued
// instructions: rcp_f64+3NR instead of IEEE div, fast sigmoid (v_exp_f32 +
// v_rcp_f32), FMA-paired dot with 0.5 folded into W (exact), inv_taum folded
// into constants, unconditional stores (pad lanes mirror lane 0 -> duplicate
// store to same addr), prefetch tail peeled (no per-step clamp).
// [3rd resubmission of round-4 kernel: three infra failures in a row,
//  change still unmeasured.]

#define T_STEPS 1024
#define BATCH   2048
#define NN      12
#define PF      8

template<int I>
__device__ __forceinline__ double rowbcast16(double x) {
    union { double d; int i2[2]; } u, r;
    u.d = x;
    r.i2[0] = __builtin_amdgcn_update_dpp(0, u.i2[0], 0x150 + I, 0xF, 0xF, true);
    r.i2[1] = __builtin_amdgcn_update_dpp(0, u.i2[1], 0x150 + I, 0xF, 0xF, true);
    return r.d;
}

template<bool USE_DPP, int I>
__device__ __forceinline__ double bc(double a) {
    if constexpr (USE_DPP) return rowbcast16<I>(a);
    else                   return __shfl(a, I, 16);
}

// 1/d via v_rcp_f64 seed + 3 Newton iterations (~1-2 ulp; d is always a
// normal positive fp64 here: th in (1e-158, 1e4], th-EL >= 56.5).
__device__ __forceinline__ double fast_rcp(double d) {
    double r = __builtin_amdgcn_rcp(d);
    r = fma(fma(-d, r, 1.0), r, r);
    r = fma(fma(-d, r, 1.0), r, r);
    r = fma(fma(-d, r, 1.0), r, r);
    return r;
}

__global__ __launch_bounds__(64) void lif_scan_kernel(
    const float* __restrict__ x,        // [T,B,N]
    const float* __restrict__ w,        // [N,N]
    const float* __restrict__ E_L,
    const float* __restrict__ tau_m,
    const float* __restrict__ tau_s,
    const float* __restrict__ Gp,
    const float* __restrict__ f_v,
    const float* __restrict__ f_I,
    const float* __restrict__ dth_s,
    const float* __restrict__ b_s,
    const float* __restrict__ delta_V,
    const float* __restrict__ nRc,
    const int*   __restrict__ ntypes,
    float* __restrict__ out)            // [T,B,N]
{
    const int lane = threadIdx.x;        // block = 1 wave
    const int g    = lane >> 4;          // batch group within wave
    const int n    = lane & 15;          // neuron slot
    const int nn   = (n < NN) ? n : 0;   // pad lanes mirror neuron 0
    const int b    = blockIdx.x * 4 + g;

    // per-neuron constants (fp64)
    const double EL   = (double)E_L[nn];
    const double fv   = (double)f_v[nn];
    const double fI   = (double)f_I[nn];
    const double DTH  = (double)dth_s[nn];
    const double dV   = (double)delta_V[nn];
    const double inv_taum = 1.0 / (double)tau_m[nn];
    const double inv_taus = 1.0 / (double)tau_s[nn];
    const double ombs = 1.0 - (double)b_s[nn];
    const double c1 = (double)Gp[nn] * inv_taum;           // G/tau_m
    const double c2 = (double)nRc[nn] * inv_taum;          // nR/tau_m
    const double c3 = 1.75 * c2;                           // 1.75*nR/tau_m

    // weight column, 0.5 pre-folded (exact pow2): W[i] = 0.5*w[i][n]*nt[i]
    double W[NN];
#pragma unroll
    for (int i = 0; i < NN; ++i) {
        double wv = 0.5 * (double)w[i * NN + nn] * (double)ntypes[i];
        if (i == nn) wv = 0.0;
        W[i] = wv;
    }

    // state
    double v  = EL;
    double s  = 0.0;
    double th = DTH;
    double Ia = 0.0;
    double inv_th    = fast_rcp(th);
    double inv_dvmax = fast_rcp(th - EL);

    const int strideT = BATCH * NN;
    const float* xp   = x + b * NN + nn;
    // pad lanes store lane-0's identical value to lane-0's address (benign dup)
    float* op = out + b * NN + nn;
    const float* xpref = xp + PF * strideT;   // running prefetch pointer

    float xbuf[PF];
#pragma unroll
    for (int k = 0; k < PF; ++k)
        xbuf[k] = xp[k * strideT];

    // one-time DPP semantics self-check (uniform across waves)
    bool dpp_ok;
    {
        double tv = (double)lane;
        double r5 = rowbcast16<5>(tv);
        dpp_ok = (__ballot(r5 == (double)((lane & 48) + 5)) == ~0ull);
    }

    auto run = [&](auto use_dpp_c) {
        constexpr bool USE_DPP = decltype(use_dpp_c)::value;

        auto block8 = [&](int t0, auto pref_c) {
            constexpr bool PREF = decltype(pref_c)::value;
#pragma unroll
            for (int k = 0; k < PF; ++k) {
                const int t = t0 + k;
                const float xcur = xbuf[k];
                if constexpr (PREF) {
                    xbuf[k] = *xpref;
                    xpref += strideT;
                }

                const double a = Ia + s;   // 0.5 folded into W

                const double b0  = bc<USE_DPP, 0>(a);
                const double b1  = bc<USE_DPP, 1>(a);
                const double b2  = bc<USE_DPP, 2>(a);
                const double b3  = bc<USE_DPP, 3>(a);
                const double b4  = bc<USE_DPP, 4>(a);
                const double b5  = bc<USE_DPP, 5>(a);
                const double b6  = bc<USE_DPP, 6>(a);
                const double b7  = bc<USE_DPP, 7>(a);
                const double b8  = bc<USE_DPP, 8>(a);
                const double b9  = bc<USE_DPP, 9>(a);
                const double b10 = bc<USE_DPP,10>(a);
                const double b11 = bc<USE_DPP,11>(a);

                const double d0 = fma(b1,  W[1],  b0  * W[0]);
                const double d1 = fma(b3,  W[3],  b2  * W[2]);
                const double d2 = fma(b5,  W[5],  b4  * W[4]);
                const double d3 = fma(b7,  W[7],  b6  * W[6]);
                const double d4 = fma(b9,  W[9],  b8  * W[8]);
                const double d5 = fma(b11, W[11], b10 * W[10]);
                const double dot = ((d0 + d1) + (d2 + d3)) + (d4 + d5);

                const double base   = fma((double)xcur, c3, c1 * (EL - v));
                const double dv     = fma(dot, c2, base);
                const double v_next = v + dv;
                const bool   spiked = (v_next >= th);

                double gating = v_next * inv_th;
                gating = fmin(fmax(gating, 0.0), 1.0);
                double rr = dv * inv_dvmax;
                rr = fmin(fmax(rr, 0.0), 1.0);

                s = fma(fma(gating, rr, -s), inv_taus, s);

                const double v_reset = fma(fv, v - EL, EL) - dV;
                const double th_new  = spiked ? (th + DTH) : (ombs * th);

                v  = spiked ? v_reset : v_next;
                Ia = fma(-fI, Ia, Ia) + (spiked ? fI : 0.0);

                const double zt = v_next - th_new;
                th = th_new;
                // reciprocals for next step — off the dependence chain
                inv_th    = fast_rcp(th);
                inv_dvmax = fast_rcp(th - EL);

                const float ez   = __expf(-(float)zt);
                const float soft = __builtin_amdgcn_rcpf(1.0f + ez);
                op[t * strideT] = soft;
            }
        };

        for (int t0 = 0; t0 < T_STEPS - PF; t0 += PF)
            block8(t0, std::true_type{});
        block8(T_STEPS - PF, std::false_type{});
    };

    if (dpp_ok) run(std::true_type{});
    else        run(std::false_type{});
}

extern "C" void kernel_launch(void* const* d_in, const int* in_sizes, int n_in,
                              void* d_out, int out_size, void* d_ws, size_t ws_size,
                              hipStream_t stream) {
    const float* x    = (const float*)d_in[0];
    const float* w    = (const float*)d_in[1];
    const float* E_L  = (const float*)d_in[2];
    const float* taum = (const float*)d_in[3];
    const float* taus = (const float*)d_in[4];
    const float* G    = (const float*)d_in[5];
    const float* f_v  = (const float*)d_in[6];
    const float* f_I  = (const float*)d_in[7];
    const float* dth  = (const float*)d_in[8];
    const float* b_s  = (const float*)d_in[9];
    const float* dV   = (const float*)d_in[10];
    const float* nRc  = (const float*)d_in[11];
    const int*   nt   = (const int*)d_in[12];
    float* outp       = (float*)d_out;

    const int blocks = BATCH / 4;  // 512 blocks x 64 threads
    lif_scan_kernel<<<blocks, 64, 0, stream>>>(
        x, w, E_L, taum, taus, G, f_v, f_I, dth, b_s, dV, nRc, nt, outp);
}

// Round 8
// 351.018 us; speedup vs baseline: 1.6631x; 1.0805x over previous
//
#include <hip/hip_runtime.h>
#include <math.h>
#include <type_traits>

// LIF_R_ASC recurrent spiking-neuron scan — fp64 state, issue-count-optimized.
// 16 lanes/batch (lane=neuron), wave64 = 4 batch elems, 512 blocks x 64.
// Wall = per-wave serial chain (each wave owns a SIMD; stream length is the
// only lever). r8: fast_rcp 3NR -> 1NR (seed^2 ~ 2^-54, correctly rounded;
// extra iters were waste), and constant folds: dv = fma(dot,c2,fma(x,c3,
// fma(-c1,v,c1EL))), v_reset = fma(fv, v-EL, EL-dV), Ia = fma(1-fI, Ia, sel).
// All ulp-class perturbations — r7 proved this class flips no spikes
// (absmax stayed exactly at the bf16 output-quantization floor).

#define T_STEPS 1024
#define BATCH   2048
#define NN      12
#define PF      8

template<int I>
__device__ __forceinline__ double rowbcast16(double x) {
    union { double d; int i2[2]; } u, r;
    u.d = x;
    r.i2[0] = __builtin_amdgcn_update_dpp(0, u.i2[0], 0x150 + I, 0xF, 0xF, true);
    r.i2[1] = __builtin_amdgcn_update_dpp(0, u.i2[1], 0x150 + I, 0xF, 0xF, true);
    return r.d;
}

template<bool USE_DPP, int I>
__device__ __forceinline__ double bc(double a) {
    if constexpr (USE_DPP) return rowbcast16<I>(a);
    else                   return __shfl(a, I, 16);
}

// 1/d via v_rcp_f64 seed + 1 Newton iteration. Seed rel-err ~2^-27 squares
// to ~2^-54 -> correctly rounded to ~1 ulp. d is always normal positive
// (th in (1e-157, 1e4], th-EL >= 56.5).
__device__ __forceinline__ double fast_rcp(double d) {
    double r = __builtin_amdgcn_rcp(d);
    r = fma(fma(-d, r, 1.0), r, r);
    return r;
}

__global__ __launch_bounds__(64) void lif_scan_kernel(
    const float* __restrict__ x,        // [T,B,N]
    const float* __restrict__ w,        // [N,N]
    const float* __restrict__ E_L,
    const float* __restrict__ tau_m,
    const float* __restrict__ tau_s,
    const float* __restrict__ Gp,
    const float* __restrict__ f_v,
    const float* __restrict__ f_I,
    const float* __restrict__ dth_s,
    const float* __restrict__ b_s,
    const float* __restrict__ delta_V,
    const float* __restrict__ nRc,
    const int*   __restrict__ ntypes,
    float* __restrict__ out)            // [T,B,N]
{
    const int lane = threadIdx.x;        // block = 1 wave
    const int g    = lane >> 4;          // batch group within wave
    const int n    = lane & 15;          // neuron slot
    const int nn   = (n < NN) ? n : 0;   // pad lanes mirror neuron 0
    const int b    = blockIdx.x * 4 + g;

    // per-neuron constants (fp64)
    const double EL   = (double)E_L[nn];
    const double fv   = (double)f_v[nn];
    const double fI   = (double)f_I[nn];
    const double DTH  = (double)dth_s[nn];
    const double dV   = (double)delta_V[nn];
    const double inv_taum = 1.0 / (double)tau_m[nn];
    const double inv_taus = 1.0 / (double)tau_s[nn];
    const double ombs = 1.0 - (double)b_s[nn];
    const double c1 = (double)Gp[nn] * inv_taum;           // G/tau_m
    const double c2 = (double)nRc[nn] * inv_taum;          // nR/tau_m
    const double c3 = 1.75 * c2;                           // 1.75*nR/tau_m
    const double c1EL  = c1 * EL;                          // G*EL/tau_m
    const double ELmdV = EL - dV;                          // reset base
    const double omfI  = 1.0 - fI;

    // weight column, 0.5 pre-folded (exact pow2): W[i] = 0.5*w[i][n]*nt[i]
    double W[NN];
#pragma unroll
    for (int i = 0; i < NN; ++i) {
        double wv = 0.5 * (double)w[i * NN + nn] * (double)ntypes[i];
        if (i == nn) wv = 0.0;
        W[i] = wv;
    }

    // state
    double v  = EL;
    double s  = 0.0;
    double th = DTH;
    double Ia = 0.0;
    double inv_th    = fast_rcp(th);
    double inv_dvmax = fast_rcp(th - EL);

    const int strideT = BATCH * NN;
    const float* xp   = x + b * NN + nn;
    // pad lanes store lane-0's identical value to lane-0's address (benign dup)
    float* op = out + b * NN + nn;
    const float* xpref = xp + PF * strideT;   // running prefetch pointer

    float xbuf[PF];
#pragma unroll
    for (int k = 0; k < PF; ++k)
        xbuf[k] = xp[k * strideT];

    // one-time DPP semantics self-check (uniform across waves)
    bool dpp_ok;
    {
        double tv = (double)lane;
        double r5 = rowbcast16<5>(tv);
        dpp_ok = (__ballot(r5 == (double)((lane & 48) + 5)) == ~0ull);
    }

    auto run = [&](auto use_dpp_c) {
        constexpr bool USE_DPP = decltype(use_dpp_c)::value;

        auto block8 = [&](int t0, auto pref_c) {
            constexpr bool PREF = decltype(pref_c)::value;
#pragma unroll
            for (int k = 0; k < PF; ++k) {
                const int t = t0 + k;
                const float xcur = xbuf[k];
                if constexpr (PREF) {
                    xbuf[k] = *xpref;
                    xpref += strideT;
                }

                const double a = Ia + s;   // 0.5 folded into W

                const double b0  = bc<USE_DPP, 0>(a);
                const double b1  = bc<USE_DPP, 1>(a);
                const double b2  = bc<USE_DPP, 2>(a);
                const double b3  = bc<USE_DPP, 3>(a);
                const double b4  = bc<USE_DPP, 4>(a);
                const double b5  = bc<USE_DPP, 5>(a);
                const double b6  = bc<USE_DPP, 6>(a);
                const double b7  = bc<USE_DPP, 7>(a);
                const double b8  = bc<USE_DPP, 8>(a);
                const double b9  = bc<USE_DPP, 9>(a);
                const double b10 = bc<USE_DPP,10>(a);
                const double b11 = bc<USE_DPP,11>(a);

                const double d0 = fma(b1,  W[1],  b0  * W[0]);
                const double d1 = fma(b3,  W[3],  b2  * W[2]);
                const double d2 = fma(b5,  W[5],  b4  * W[4]);
                const double d3 = fma(b7,  W[7],  b6  * W[6]);
                const double d4 = fma(b9,  W[9],  b8  * W[8]);
                const double d5 = fma(b11, W[11], b10 * W[10]);
                const double dot = ((d0 + d1) + (d2 + d3)) + (d4 + d5);

                const double dv     = fma(dot, c2,
                                      fma((double)xcur, c3,
                                      fma(-c1, v, c1EL)));
                const double v_next = v + dv;
                const bool   spiked = (v_next >= th);

                double gating = v_next * inv_th;
                gating = fmin(fmax(gating, 0.0), 1.0);
                double rr = dv * inv_dvmax;
                rr = fmin(fmax(rr, 0.0), 1.0);

                s = fma(fma(gating, rr, -s), inv_taus, s);

                const double v_reset = fma(fv, v - EL, ELmdV);
                const double th_new  = spiked ? (th + DTH) : (ombs * th);

                v  = spiked ? v_reset : v_next;
                Ia = fma(omfI, Ia, spiked ? fI : 0.0);

                const double zt = v_next - th_new;
                th = th_new;
                // reciprocals for next step — off the dependence chain
                inv_th    = fast_rcp(th);
                inv_dvmax = fast_rcp(th - EL);

                const float ez   = __expf(-(float)zt);
                const float soft = __builtin_amdgcn_rcpf(1.0f + ez);
                op[t * strideT] = soft;
            }
        };

        for (int t0 = 0; t0 < T_STEPS - PF; t0 += PF)
            block8(t0, std::true_type{});
        block8(T_STEPS - PF, std::false_type{});
    };

    if (dpp_ok) run(std::true_type{});
    else        run(std::false_type{});
}

extern "C" void kernel_launch(void* const* d_in, const int* in_sizes, int n_in,
                              void* d_out, int out_size, void* d_ws, size_t ws_size,
                              hipStream_t stream) {
    const float* x    = (const float*)d_in[0];
    const float* w    = (const float*)d_in[1];
    const float* E_L  = (const float*)d_in[2];
    const float* taum = (const float*)d_in[3];
    const float* taus = (const float*)d_in[4];
    const float* G    = (const float*)d_in[5];
    const float* f_v  = (const float*)d_in[6];
    const float* f_I  = (const float*)d_in[7];
    const float* dth  = (const float*)d_in[8];
    const float* b_s  = (const float*)d_in[9];
    const float* dV   = (const float*)d_in[10];
    const float* nRc  = (const float*)d_in[11];
    const int*   nt   = (const int*)d_in[12];
    float* outp       = (float*)d_out;

    const int blocks = BATCH / 4;  // 512 blocks x 64 threads
    lif_scan_kernel<<<blocks, 64, 0, stream>>>(
        x, w, E_L, taum, taus, G, f_v, f_I, dth, b_s, dV, nRc, nt, outp);
}